// Round 17
// baseline (39.876 us; speedup 1.0000x reference)
//
#include <hip/hip_runtime.h>

typedef float f32x4 __attribute__((ext_vector_type(4)));

// out[b][v][p][i][s] = shell[s]*sh[i] / norm[b][l(i)][s]
// B=8 V=2048 P=32 I=16 S=4, monoms=20
// k1: 2048 blk -> partials[2048][16]  (unchanged)
// k3: FAT staging: production computes sh[16]+sl[4] per point -> LDS[256][20];
//     consumption = {ds_read b32 + b128 + 4 mul + dense plain store} per iter.

__device__ __forceinline__ void compute_monoms(float nx, float ny, float nz, float* m) {
    float zp2 = nz*nz, zp3 = zp2*nz;
    float yp2 = ny*ny, yp3 = yp2*ny;
    float xp2 = nx*nx, xp3 = xp2*nx;
    m[0]=1.0f;  m[1]=nz;       m[2]=zp2;      m[3]=zp3;
    m[4]=ny;    m[5]=ny*nz;    m[6]=ny*zp2;
    m[7]=yp2;   m[8]=yp2*nz;   m[9]=yp3;
    m[10]=nx;   m[11]=nx*nz;   m[12]=nx*zp2;
    m[13]=nx*ny; m[14]=nx*ny*nz; m[15]=nx*yp2;
    m[16]=xp2;  m[17]=xp2*nz;  m[18]=xp2*ny;
    m[19]=xp3;
}

__device__ __forceinline__ void compute_shells(float dist, float* sl) {
    const float B1 = 32.0f/3.0f, B2 = 64.0f/3.0f, B3 = 32.0f;
    const float C1 = -16.0f/9.0f, C2 = -64.0f/9.0f, C3 = -16.0f;
    float nd2 = -16.0f * dist * dist;
    sl[0] = __expf(nd2);
    sl[1] = __expf(fmaf(B1, dist, nd2 + C1));
    sl[2] = __expf(fmaf(B2, dist, nd2 + C2));
    sl[3] = __expf(fmaf(B3, dist, nd2 + C3));
    float den = sl[0] + sl[1] + sl[2] + sl[3];
    float r = 1.0f / fmaxf(den, 1e-6f);
    float mask = (dist <= 1.0f) ? r : 0.0f;
#pragma unroll
    for (int s = 0; s < 4; ++s) sl[s] *= mask;
}

// ---------------- K1: 2048 blocks, 8 units -> block-sum -> partials[blk][16] ----------------
__global__ __launch_bounds__(256) void sh_k1(const float* __restrict__ patches,
                                             const float* __restrict__ Y,
                                             float* __restrict__ partials) {
    __shared__ float sh2_lds[8][32][17];
    __shared__ float shl2_lds[8][32][5];
    __shared__ float l2_lds[8][16][4];
    __shared__ float red[8][16];

    const int tid  = threadIdx.x;
    const int wv   = tid >> 6;
    const int lane = tid & 63;
    const int half = lane >> 5;
    const int p    = lane & 31;
    const int u    = wv * 2 + half;
    const int unit = blockIdx.x * 8 + u;

    const float* pp = patches + ((size_t)unit * 32 + p) * 3;
    float x = pp[0], y = pp[1], z = pp[2];
    float dist = sqrtf(x*x + y*y + z*z);
    float inv  = 1.0f / fmaxf(dist, 1e-6f);
    float nx = -x*inv, ny = -y*inv, nz = -z*inv;
    float m[20];
    compute_monoms(nx, ny, nz, m);

#pragma unroll
    for (int i = 0; i < 16; ++i) {
        float acc = 0.f;
#pragma unroll
        for (int j = 0; j < 20; ++j)
            acc = fmaf(Y[i*20 + j], m[j], acc);   // uniform -> s_load
        sh2_lds[u][p][i] = acc * acc;
    }
    float sl[4];
    compute_shells(dist, sl);
#pragma unroll
    for (int s = 0; s < 4; ++s) shl2_lds[u][p][s] = sl[s]*sl[s];
    __syncthreads();

    const int ri = lane >> 2, rs = lane & 3;
    const int u0 = wv*2, u1 = wv*2 + 1;
    float acc0 = 0.f, acc1 = 0.f;
#pragma unroll
    for (int q = 0; q < 32; ++q) {
        acc0 = fmaf(sh2_lds[u0][q][ri], shl2_lds[u0][q][rs], acc0);
        acc1 = fmaf(sh2_lds[u1][q][ri], shl2_lds[u1][q][rs], acc1);
    }
    l2_lds[u0][ri][rs] = acc0;
    l2_lds[u1][ri][rs] = acc1;
    __syncthreads();

    if (lane < 32) {
        const int h2 = lane >> 4;
        const int c  = lane & 15;            // c = l*4 + s
        const int l  = c >> 2, s = c & 3;
        const int uu = wv*2 + h2;
        const int start = l*l, cnt = 2*l + 1;
        float acc = 0.f;
        for (int t = 0; t < cnt; ++t) acc += l2_lds[uu][start + t][s];
        red[uu][c] = sqrtf(acc);
    }
    __syncthreads();
    if (tid < 16) {
        float s2 = 0.f;
#pragma unroll
        for (int uu = 0; uu < 8; ++uu) s2 += red[uu][tid];
        partials[blockIdx.x*16 + tid] = s2;   // deterministic, no atomics
    }
}

// ---------------- K3: FAT staging + minimal consumption loop ----------------
__global__ __launch_bounds__(256) void sh_k3(const float* __restrict__ patches,
                                             const float* __restrict__ Y,
                                             const float* __restrict__ partials,
                                             f32x4* __restrict__ out) {
    __shared__ float sts[256][20];     // [0..15]=sh[i], [16..19]=sl[s]
    __shared__ float pr[16][17];
    __shared__ float rcp_lds[16];

    const int tid = threadIdx.x;
    const int blk = blockIdx.x;        // 0..2047, 256 blocks per batch
    const int bb  = blk >> 8;          // batch

    // ---- issue partial loads EARLY (hide latency under production) ----
    const int ch = tid & 15, r0 = tid >> 4;   // r0 0..15
    float pl[16];
#pragma unroll
    for (int r = 0; r < 16; ++r)
        pl[r] = partials[((size_t)bb*256 + r0 + r*16)*16 + ch];

    // ---- production: full per-point work ONCE -> LDS ----
    {
        const size_t ptg = (size_t)blk*256 + tid;
        const float* pp = patches + ptg*3;
        float x = pp[0], y = pp[1], z = pp[2];
        float dist = sqrtf(x*x + y*y + z*z);
        float inv  = 1.0f / fmaxf(dist, 1e-6f);
        float nx = -x*inv, ny = -y*inv, nz = -z*inv;
        float m[20];
        compute_monoms(nx, ny, nz, m);
#pragma unroll
        for (int i = 0; i < 16; ++i) {
            float acc = 0.f;
#pragma unroll
            for (int j = 0; j < 20; ++j)
                acc = fmaf(Y[i*20 + j], m[j], acc);   // uniform -> s_load
            sts[tid][i] = acc;
        }
        float sl[4];
        compute_shells(dist, sl);
        *(f32x4*)&sts[tid][16] = f32x4{ sl[0], sl[1], sl[2], sl[3] };
    }
    // ---- fold partials ----
    {
        float a = 0.f;
#pragma unroll
        for (int r = 0; r < 16; ++r) a += pl[r];
        pr[r0][ch] = a;
    }
    __syncthreads();
    if (tid < 16) {
        float s = 0.f;
#pragma unroll
        for (int r = 0; r < 16; ++r) s += pr[r][tid];
        float meanv = s * (1.0f/2048.0f);
        rcp_lds[tid] = 1.0f / fmaxf(meanv, 1e-8f);
    }
    __syncthreads();

    // ---- consumption: lane -> (pgrp, i); dense 1KB wave stores, tiny body ----
    const int i    = tid & 15;          // output row
    const int pgrp = tid >> 4;          // 0..15

    const int l = (i == 0) ? 0 : ((i < 4) ? 1 : ((i < 9) ? 2 : 3));
    const float rc0=rcp_lds[l*4+0], rc1=rcp_lds[l*4+1], rc2=rcp_lds[l*4+2], rc3=rcp_lds[l*4+3];

#pragma unroll 4
    for (int it2 = 0; it2 < 16; ++it2) {
        const int r = it2*16 + pgrp;    // staged point row
        float sh  = sts[r][i];
        f32x4 s4  = *(const f32x4*)&sts[r][16];

        const size_t pt = (size_t)blk*256 + r;
        f32x4 o;
        o.x = sh*s4.x*rc0;
        o.y = sh*s4.y*rc1;
        o.z = sh*s4.z*rc2;
        o.w = sh*s4.w*rc3;
        out[pt*16 + i] = o;             // plain store (R16 keeper)
    }
}

extern "C" void kernel_launch(void* const* d_in, const int* in_sizes, int n_in,
                              void* d_out, int out_size, void* d_ws, size_t ws_size,
                              hipStream_t stream) {
    const float* patches = (const float*)d_in[0];   // 8*2048*32*3
    const float* Y       = (const float*)d_in[1];   // 16*20
    f32x4* out4 = (f32x4*)d_out;

    float* partials = (float*)d_ws;                 // 2048*16 floats = 128 KB

    sh_k1<<<2048, 256, 0, stream>>>(patches, Y, partials);
    sh_k3<<<2048, 256, 0, stream>>>(patches, Y, partials, out4);
}

// Round 18
// 37.256 us; speedup vs baseline: 1.0703x; 1.0703x over previous
//
#include <hip/hip_runtime.h>

typedef float f32x4 __attribute__((ext_vector_type(4)));

// out[b][v][p][i][s] = shell[s]*sh[i] / norm[b][l(i)][s]
// B=8 V=2048 P=32 I=16 S=4, monoms=20
// k1: phase-B reduce via b128 LDS reads + shfl_xor fold (was 128 scalar ds_read/wave)
// k3: EXACT R16 keeper (slim stage, plain dense stores, 37.0us baseline)

__device__ __forceinline__ void compute_monoms(float nx, float ny, float nz, float* m) {
    float zp2 = nz*nz, zp3 = zp2*nz;
    float yp2 = ny*ny, yp3 = yp2*ny;
    float xp2 = nx*nx, xp3 = xp2*nx;
    m[0]=1.0f;  m[1]=nz;       m[2]=zp2;      m[3]=zp3;
    m[4]=ny;    m[5]=ny*nz;    m[6]=ny*zp2;
    m[7]=yp2;   m[8]=yp2*nz;   m[9]=yp3;
    m[10]=nx;   m[11]=nx*nz;   m[12]=nx*zp2;
    m[13]=nx*ny; m[14]=nx*ny*nz; m[15]=nx*yp2;
    m[16]=xp2;  m[17]=xp2*nz;  m[18]=xp2*ny;
    m[19]=xp3;
}

__device__ __forceinline__ void compute_shells(float dist, float* sl) {
    const float B1 = 32.0f/3.0f, B2 = 64.0f/3.0f, B3 = 32.0f;
    const float C1 = -16.0f/9.0f, C2 = -64.0f/9.0f, C3 = -16.0f;
    float nd2 = -16.0f * dist * dist;
    sl[0] = __expf(nd2);
    sl[1] = __expf(fmaf(B1, dist, nd2 + C1));
    sl[2] = __expf(fmaf(B2, dist, nd2 + C2));
    sl[3] = __expf(fmaf(B3, dist, nd2 + C3));
    float den = sl[0] + sl[1] + sl[2] + sl[3];
    float r = 1.0f / fmaxf(den, 1e-6f);
    float mask = (dist <= 1.0f) ? r : 0.0f;
#pragma unroll
    for (int s = 0; s < 4; ++s) sl[s] *= mask;
}

// ---------------- K1: 2048 blocks, 8 units; b128 reduce ----------------
__global__ __launch_bounds__(256) void sh_k1(const float* __restrict__ patches,
                                             const float* __restrict__ Y,
                                             float* __restrict__ partials) {
    __shared__ float comb[8][32][20];   // [0..15]=sh^2, [16..19]=sl^2; 80B rows (16B-aligned)
    __shared__ float l2t[8][4][20];     // transposed: [u][s][i], b128-writable
    __shared__ float red[8][16];

    const int tid  = threadIdx.x;
    const int wv   = tid >> 6;
    const int lane = tid & 63;
    const int half = lane >> 5;
    const int p    = lane & 31;
    const int u    = wv * 2 + half;
    const int unit = blockIdx.x * 8 + u;

    // ---- phase A: per-point compute (unchanged math), b128 LDS writes ----
    {
        const float* pp = patches + ((size_t)unit * 32 + p) * 3;
        float x = pp[0], y = pp[1], z = pp[2];
        float dist = sqrtf(x*x + y*y + z*z);
        float inv  = 1.0f / fmaxf(dist, 1e-6f);
        float nx = -x*inv, ny = -y*inv, nz = -z*inv;
        float m[20];
        compute_monoms(nx, ny, nz, m);

        float sh2[16];
#pragma unroll
        for (int i = 0; i < 16; ++i) {
            float acc = 0.f;
#pragma unroll
            for (int j = 0; j < 20; ++j)
                acc = fmaf(Y[i*20 + j], m[j], acc);   // uniform -> s_load
            sh2[i] = acc * acc;
        }
        float sl[4];
        compute_shells(dist, sl);
#pragma unroll
        for (int k = 0; k < 4; ++k)
            *(f32x4*)&comb[u][p][k*4] = f32x4{ sh2[k*4+0], sh2[k*4+1], sh2[k*4+2], sh2[k*4+3] };
        *(f32x4*)&comb[u][p][16] = f32x4{ sl[0]*sl[0], sl[1]*sl[1], sl[2]*sl[2], sl[3]*sl[3] };
    }
    __syncthreads();

    // ---- phase B: lane <-> (qq, ib, s); b128 reads + shfl fold over qq ----
    const int qq = lane >> 4;            // q-slice 0..3
    const int ib = (lane >> 2) & 3;      // i-block 0..3
    const int s  = lane & 3;
    const int u0 = wv*2, u1 = wv*2 + 1;

#pragma unroll
    for (int uu = 0; uu < 2; ++uu) {
        const int uc = (uu == 0) ? u0 : u1;
        f32x4 acc = { 0.f, 0.f, 0.f, 0.f };
#pragma unroll
        for (int j = 0; j < 8; ++j) {
            const int q = qq*8 + j;
            f32x4 sh4 = *(const f32x4*)&comb[uc][q][ib*4];
            float sl2v = comb[uc][q][16 + s];
            acc.x = fmaf(sh4.x, sl2v, acc.x);
            acc.y = fmaf(sh4.y, sl2v, acc.y);
            acc.z = fmaf(sh4.z, sl2v, acc.z);
            acc.w = fmaf(sh4.w, sl2v, acc.w);
        }
        // fold over qq (lanes stride 16): xor 16 then 32
        acc.x += __shfl_xor(acc.x, 16); acc.y += __shfl_xor(acc.y, 16);
        acc.z += __shfl_xor(acc.z, 16); acc.w += __shfl_xor(acc.w, 16);
        acc.x += __shfl_xor(acc.x, 32); acc.y += __shfl_xor(acc.y, 32);
        acc.z += __shfl_xor(acc.z, 32); acc.w += __shfl_xor(acc.w, 32);
        if (qq == 0)
            *(f32x4*)&l2t[uc][s][ib*4] = acc;
    }
    __syncthreads();

    // ---- phase C: group-sum over i within l, sqrt -> red ----
    if (lane < 32) {
        const int h2 = lane >> 4;
        const int c  = lane & 15;            // c = l*4 + s
        const int l  = c >> 2, sc = c & 3;
        const int uc = wv*2 + h2;
        const int start = l*l, cnt = 2*l + 1;
        float acc = 0.f;
        for (int t = 0; t < cnt; ++t) acc += l2t[uc][sc][start + t];
        red[uc][c] = sqrtf(acc);
    }
    __syncthreads();
    if (tid < 16) {
        float s2 = 0.f;
#pragma unroll
        for (int uc = 0; uc < 8; ++uc) s2 += red[uc][tid];
        partials[blockIdx.x*16 + tid] = s2;   // deterministic, no atomics
    }
}

// ---------------- K3: EXACT R16 keeper ----------------
__global__ __launch_bounds__(256) void sh_k3(const float* __restrict__ patches,
                                             const float* __restrict__ Y,
                                             const float* __restrict__ partials,
                                             f32x4* __restrict__ out) {
    __shared__ float mon[256][12];     // [0..2]=n, [4..7]=sl, stride 12
    __shared__ float pr[16][17];
    __shared__ float rcp_lds[16];

    const int tid = threadIdx.x;
    const int blk = blockIdx.x;        // 0..2047, 256 blocks per batch
    const int bb  = blk >> 8;          // batch

    const int ch = tid & 15, r0 = tid >> 4;
    float pl[16];
#pragma unroll
    for (int r = 0; r < 16; ++r)
        pl[r] = partials[((size_t)bb*256 + r0 + r*16)*16 + ch];

    {
        const size_t ptg = (size_t)blk*256 + tid;
        const float* pp = patches + ptg*3;
        float x = pp[0], y = pp[1], z = pp[2];
        float dist = sqrtf(x*x + y*y + z*z);
        float inv  = 1.0f / fmaxf(dist, 1e-6f);
        float sl[4];
        compute_shells(dist, sl);
        f32x4 n4 = { -x*inv, -y*inv, -z*inv, 0.f };
        f32x4 s4 = { sl[0], sl[1], sl[2], sl[3] };
        *(f32x4*)&mon[tid][0] = n4;
        *(f32x4*)&mon[tid][4] = s4;
    }
    {
        float a = 0.f;
#pragma unroll
        for (int r = 0; r < 16; ++r) a += pl[r];
        pr[r0][ch] = a;
    }
    __syncthreads();
    if (tid < 16) {
        float s = 0.f;
#pragma unroll
        for (int r = 0; r < 16; ++r) s += pr[r][tid];
        float meanv = s * (1.0f/2048.0f);
        rcp_lds[tid] = 1.0f / fmaxf(meanv, 1e-8f);
    }
    __syncthreads();

    const int i    = tid & 15;
    const int pgrp = tid >> 4;

    const float4* Y4 = (const float4*)Y;
    float yr[20];
#pragma unroll
    for (int q = 0; q < 5; ++q) {
        float4 t = Y4[i*5 + q];
        yr[q*4+0]=t.x; yr[q*4+1]=t.y; yr[q*4+2]=t.z; yr[q*4+3]=t.w;
    }
    const int l = (i == 0) ? 0 : ((i < 4) ? 1 : ((i < 9) ? 2 : 3));
    const float rc0=rcp_lds[l*4+0], rc1=rcp_lds[l*4+1], rc2=rcp_lds[l*4+2], rc3=rcp_lds[l*4+3];

#pragma unroll 2
    for (int it2 = 0; it2 < 16; ++it2) {
        const int r = it2*16 + pgrp;
        f32x4 n4 = *(const f32x4*)&mon[r][0];
        f32x4 s4 = *(const f32x4*)&mon[r][4];

        float m[20];
        compute_monoms(n4.x, n4.y, n4.z, m);

        float sh = 0.f;
#pragma unroll
        for (int j = 0; j < 20; ++j)
            sh = fmaf(yr[j], m[j], sh);

        const size_t pt = (size_t)blk*256 + r;
        f32x4 o;
        o.x = sh*s4.x*rc0;
        o.y = sh*s4.y*rc1;
        o.z = sh*s4.z*rc2;
        o.w = sh*s4.w*rc3;
        out[pt*16 + i] = o;             // plain store (R16 keeper)
    }
}

extern "C" void kernel_launch(void* const* d_in, const int* in_sizes, int n_in,
                              void* d_out, int out_size, void* d_ws, size_t ws_size,
                              hipStream_t stream) {
    const float* patches = (const float*)d_in[0];   // 8*2048*32*3
    const float* Y       = (const float*)d_in[1];   // 16*20
    f32x4* out4 = (f32x4*)d_out;

    float* partials = (float*)d_ws;                 // 2048*16 floats = 128 KB

    sh_k1<<<2048, 256, 0, stream>>>(patches, Y, partials);
    sh_k3<<<2048, 256, 0, stream>>>(patches, Y, partials, out4);
}